// Round 17
// baseline (510.778 us; speedup 1.0000x reference)
//
#include <hip/hip_runtime.h>
#include <hip/hip_bf16.h>
#include <cstdint>

#define B_DIM 2
#define S_LEN 2048
#define HID 4096
#define NH 32
#define NKV 8
#define HD 128
#define QSZ (NH * HD)          // 4096
#define KVSZ (NKV * HD)        // 1024
#define QKVW (QSZ + 2 * KVSZ)  // 6144
#define SCALING 0.08838834764831845f

typedef __bf16 bf16;
typedef __bf16 bf16x4 __attribute__((ext_vector_type(4)));
typedef __bf16 bf16x8 __attribute__((ext_vector_type(8)));
typedef float floatx4 __attribute__((ext_vector_type(4)));
typedef float floatx16 __attribute__((ext_vector_type(16)));

typedef __attribute__((address_space(1))) void GV;
typedef __attribute__((address_space(3))) void SV;

#define BAR() __builtin_amdgcn_s_barrier()
#define SCHED_FENCE() __builtin_amdgcn_sched_barrier(0)

// ---------------- fused f32 -> bf16 convert (2 buffers, 1 launch) ----------------
__global__ __launch_bounds__(256) void cvt2(const float* __restrict__ a, bf16* __restrict__ oa, int na4,
                                            const float* __restrict__ b, bf16* __restrict__ ob, int nb4) {
    int total = na4 + nb4;
    int stride = gridDim.x * blockDim.x;
    for (int i = blockIdx.x * blockDim.x + threadIdx.x; i < total; i += stride) {
        const float* src; bf16* dst; int j = i;
        if (j < na4) { src = a; dst = oa; }
        else { j -= na4; src = b; dst = ob; }
        float4 v = ((const float4*)src)[j];
        bf16x4 o;
        o[0] = (bf16)v.x; o[1] = (bf16)v.y; o[2] = (bf16)v.z; o[3] = (bf16)v.w;
        ((bf16x4*)dst)[j] = o;
    }
}

// ---------------- 256x256 GEMM, 32x32x16 MFMA, 4 barriers / 2 K-tiles ----------------
// Phase grouping by row-group x col-frag keeps A/B read windows and the stage ring
// IDENTICAL to the verified 16x16 schedule: A(dbuf) read P0,P2; B(dbuf) read P0,P1;
// stages {P0/P1: A(nxt); P2/P3: B(nxt2); ...}; vmcnt(4) at P3/P7; barriers after P1/P3/P5/P7.
// C/D layout (verified m74/m101): col=lane&31, row=(reg&3)+8*(reg>>2)+4*(lane>>5).
// MODE 0: plain C write. MODE 1: fused RoPE/QKV epilogue. blockIdx >= ngemm: backfill cvt.
template <int MODE, typename OutT>
__global__ __launch_bounds__(512, 2) void gemm256(const bf16* __restrict__ A,
                                                  const bf16* __restrict__ Bm,
                                                  OutT* __restrict__ C,
                                                  bf16* __restrict__ Qo,
                                                  bf16* __restrict__ Ko,
                                                  bf16* __restrict__ Vo,
                                                  const float* __restrict__ cosp,
                                                  const float* __restrict__ sinp,
                                                  const float* __restrict__ cvt_src,
                                                  bf16* __restrict__ cvt_dst,
                                                  int cvt_n4, int ngemm,
                                                  int M, int N, int K) {
    __shared__ __align__(16) char smem[131072];
    (void)M;
    int bid = blockIdx.x;
    int tid = threadIdx.x;
    if (bid >= ngemm) {
        int stride = (gridDim.x - ngemm) * 512;
        for (int i = (bid - ngemm) * 512 + tid; i < cvt_n4; i += stride) {
            float4 v = ((const float4*)cvt_src)[i];
            bf16x4 o;
            o[0] = (bf16)v.x; o[1] = (bf16)v.y; o[2] = (bf16)v.z; o[3] = (bf16)v.w;
            ((bf16x4*)cvt_dst)[i] = o;
        }
        return;
    }
    int tiles_n = N >> 8;
    int wg = (bid & 7) * (ngemm >> 3) + (bid >> 3);  // XCD chunking (ngemm % 8 == 0)
    int bm = wg / tiles_n, bn = wg % tiles_n;
    int lane = tid & 63, w = tid >> 6;
    int l15 = lane & 15, lg = lane >> 4;
    int l31 = lane & 31, lh = lane >> 5;
    int wm = w >> 2, wn = w & 3;
    const bf16* Ab = A + (size_t)bm * 256 * K;
    const bf16* Bb = Bm + (size_t)bn * 256 * K;

    auto AsP = [&](int buf, int h) -> char* { return smem + (buf * 2 + h) * 16384; };
    auto BsP = [&](int buf, int h) -> char* { return smem + 65536 + (buf * 2 + h) * 16384; };

    int o_lo = tid * 16, o_hi = o_lo + 8192;
    int r_lo = o_lo >> 7, r_hi = o_hi >> 7;
    int eo0 = r_lo * K + ((((o_lo >> 4) & 7) ^ (r_lo & 7)) << 3);
    int eo1 = r_hi * K + ((((o_hi >> 4) & 7) ^ (r_hi & 7)) << 3);
    const bf16* AbH[2] = {Ab, Ab + (size_t)128 * K};
    const bf16* BbH[2] = {Bb, Bb + (size_t)128 * K};

    auto stageA = [&](int buf, int h, int kt) {
        const bf16* base = AbH[h] + kt * 64;
        __builtin_amdgcn_global_load_lds((GV*)(base + eo0), (SV*)(AsP(buf, h) + o_lo), 16, 0, 0);
        __builtin_amdgcn_global_load_lds((GV*)(base + eo1), (SV*)(AsP(buf, h) + o_hi), 16, 0, 0);
    };
    auto stageB = [&](int buf, int h, int kt) {
        const bf16* base = BbH[h] + kt * 64;
        __builtin_amdgcn_global_load_lds((GV*)(base + eo0), (SV*)(BsP(buf, h) + o_lo), 16, 0, 0);
        __builtin_amdgcn_global_load_lds((GV*)(base + eo1), (SV*)(BsP(buf, h) + o_hi), 16, 0, 0);
    };
    // 32x32x16 fragment reads: lane holds row (lane&31), k-chunk (lane>>5)*8 of kstep ks
    auto rdA32 = [&](int buf, int fr, int ks) -> bf16x8 {
        int row = fr * 32 + l31;
        int off = row * 128 + ((((ks << 1) | lh) ^ (row & 7)) << 4);
        return *(const bf16x8*)(AsP(buf, wm) + off);
    };
    auto rdB32 = [&](int buf, int fc, int ks) -> bf16x8 {
        int row = (wn & 1) * 64 + fc * 32 + l31;
        int off = row * 128 + ((((ks << 1) | lh) ^ (row & 7)) << 4);
        return *(const bf16x8*)(BsP(buf, wn >> 1) + off);
    };

    floatx16 acc[4][2] = {};
    bf16x8 aF[2][4], bF[2][4];
    int nk = K >> 6, niter = nk >> 1;

    stageA(0, 0, 0); stageA(0, 1, 0); stageB(0, 0, 0); stageB(0, 1, 0);
    stageB(1, 0, 1); stageB(1, 1, 1);
    asm volatile("s_waitcnt vmcnt(4)" ::: "memory");
    SCHED_FENCE();
    BAR();

    auto quad32 = [&](int rg, int fc) {
        __builtin_amdgcn_s_setprio(1);
#pragma unroll
        for (int ks = 0; ks < 4; ++ks)
#pragma unroll
            for (int fi = 0; fi < 2; ++fi)
                acc[rg * 2 + fi][fc] = __builtin_amdgcn_mfma_f32_32x32x16_bf16(
                    aF[fi][ks], bF[fc][ks], acc[rg * 2 + fi][fc], 0, 0, 0);
        __builtin_amdgcn_s_setprio(0);
    };

    for (int i = 0; i < niter; ++i) {
        bool nl = (i + 1 < niter);
        int kt1 = 2 * i + 1, kt2 = 2 * i + 2, kt3 = 2 * i + 3;
        // P0 (no barrier after): A rows 0-63 + B cols 0-31 of dbuf0
#pragma unroll
        for (int fi = 0; fi < 2; ++fi)
#pragma unroll
            for (int ks = 0; ks < 4; ++ks) aF[fi][ks] = rdA32(0, fi, ks);
#pragma unroll
        for (int ks = 0; ks < 4; ++ks) bF[0][ks] = rdB32(0, 0, ks);
        stageA(1, 0, kt1);
        quad32(0, 0);
        // P1: B cols 32-63
#pragma unroll
        for (int ks = 0; ks < 4; ++ks) bF[1][ks] = rdB32(0, 1, ks);
        stageA(1, 1, kt1);
        quad32(0, 1); BAR();
        // P2 (no barrier after): A rows 64-127
#pragma unroll
        for (int fi = 0; fi < 2; ++fi)
#pragma unroll
            for (int ks = 0; ks < 4; ++ks) aF[fi][ks] = rdA32(0, 2 + fi, ks);
        if (nl) stageB(0, 0, kt2);
        quad32(1, 0);
        // P3
        if (nl) stageB(0, 1, kt2);
        quad32(1, 1);
        if (nl) asm volatile("s_waitcnt vmcnt(4)" ::: "memory");
        else    asm volatile("s_waitcnt vmcnt(0)" ::: "memory");
        SCHED_FENCE();
        BAR();
        // P4 (no barrier after): dbuf1
#pragma unroll
        for (int fi = 0; fi < 2; ++fi)
#pragma unroll
            for (int ks = 0; ks < 4; ++ks) aF[fi][ks] = rdA32(1, fi, ks);
#pragma unroll
        for (int ks = 0; ks < 4; ++ks) bF[0][ks] = rdB32(1, 0, ks);
        if (nl) stageA(0, 0, kt2);
        quad32(0, 0);
        // P5
#pragma unroll
        for (int ks = 0; ks < 4; ++ks) bF[1][ks] = rdB32(1, 1, ks);
        if (nl) stageA(0, 1, kt2);
        quad32(0, 1); BAR();
        // P6 (no barrier after)
#pragma unroll
        for (int fi = 0; fi < 2; ++fi)
#pragma unroll
            for (int ks = 0; ks < 4; ++ks) aF[fi][ks] = rdA32(1, 2 + fi, ks);
        if (nl) stageB(1, 0, kt3);
        quad32(1, 0);
        // P7
        if (nl) stageB(1, 1, kt3);
        quad32(1, 1);
        asm volatile("s_waitcnt vmcnt(4)" ::: "memory");
        SCHED_FENCE();
        BAR();
    }

    if constexpr (MODE == 0) {
        int brow = bm * 256 + wm * 128, bcol = bn * 256 + wn * 64;
#pragma unroll
        for (int fr = 0; fr < 4; ++fr)
#pragma unroll
            for (int fc = 0; fc < 2; ++fc) {
                int col = bcol + fc * 32 + l31;
#pragma unroll
                for (int reg = 0; reg < 16; ++reg) {
                    int row = brow + fr * 32 + (reg & 3) + 8 * (reg >> 2) + 4 * lh;
                    C[(size_t)row * N + col] = (OutT)acc[fr][fc][reg];
                }
            }
    } else {
        __syncthreads();  // all LDS reads of As/Bs done; safe to overwrite
        int b = (bm * 256) >> 11, s0 = (bm * 256) & (S_LEN - 1);
        int colb = wn * 64, rowb = wm * 128;
        if (bn < 20) {
            // ---- row-major bounce: Cb[row][swz(col)] ----
            bf16* Cb = (bf16*)smem;
#pragma unroll
            for (int fr = 0; fr < 4; ++fr)
#pragma unroll
                for (int fc = 0; fc < 2; ++fc) {
                    int col = colb + fc * 32 + l31;
#pragma unroll
                    for (int reg = 0; reg < 16; ++reg) {
                        int row = rowb + fr * 32 + (reg & 3) + 8 * (reg >> 2) + 4 * lh;
                        Cb[row * 256 + ((((col >> 3) ^ (row & 7)) << 3) | (col & 7))] =
                            (bf16)acc[fr][fc][reg];
                    }
                }
            __syncthreads();
            // ---- Q (bn<16) or K (16..19): RoPE + write [.,H,S,D] ----
            bool isQ = (bn < 16);
            int hh = w & 1;
            int c = l15, d0 = c * 8;
            float scale = isQ ? SCALING : 1.0f;
            float sgn = (c < 8) ? -1.0f : 1.0f;
            bf16* Ob = isQ ? (Qo + ((size_t)(b * NH + bn * 2 + hh) * S_LEN) * HD)
                           : (Ko + ((size_t)(b * NKV + (bn - 16) * 2 + hh) * S_LEN) * HD);
            int slot_s = hh * 16 + c, slot_p = hh * 16 + (c ^ 8);
#pragma unroll
            for (int rd = 0; rd < 16; ++rd) {
                int row = (w >> 1) * 64 + rd * 4 + lg;
                int s = s0 + row;
                bf16x8 xs = *(const bf16x8*)(Cb + row * 256 + ((slot_s ^ (row & 7)) << 3));
                bf16x8 xp = *(const bf16x8*)(Cb + row * 256 + ((slot_p ^ (row & 7)) << 3));
                const float* cr = cosp + ((size_t)b * S_LEN + s) * HD + d0;
                const float* sr = sinp + ((size_t)b * S_LEN + s) * HD + d0;
                float4 c0 = *(const float4*)cr, c1 = *(const float4*)(cr + 4);
                float4 s0v = *(const float4*)sr, s1v = *(const float4*)(sr + 4);
                float cv[8] = {c0.x, c0.y, c0.z, c0.w, c1.x, c1.y, c1.z, c1.w};
                float sv[8] = {s0v.x, s0v.y, s0v.z, s0v.w, s1v.x, s1v.y, s1v.z, s1v.w};
                bf16x8 o;
#pragma unroll
                for (int e = 0; e < 8; ++e)
                    o[e] = (bf16)(((float)xs[e] * cv[e] + sgn * (float)xp[e] * sv[e]) * scale);
                *(bf16x8*)(Ob + (size_t)s * HD + d0) = o;
            }
        } else {
            // ---- V (bn 20..23): transposed bounce Cbt[col][swz(row)] -> Vt[B,NKV,HD,S] ----
#pragma unroll
            for (int fr = 0; fr < 4; ++fr)
#pragma unroll
                for (int fc = 0; fc < 2; ++fc) {
                    int col = colb + fc * 32 + l31;
#pragma unroll
                    for (int reg = 0; reg < 16; ++reg) {
                        int row = rowb + fr * 32 + (reg & 3) + 8 * (reg >> 2) + 4 * lh;
                        *(bf16*)(smem + col * 512 +
                                 (((((row >> 3) ^ (col & 7)) << 4) | ((row & 7) << 1)))) =
                            (bf16)acc[fr][fc][reg];
                    }
                }
            __syncthreads();
            int kvb = (bn - 20) * 2;
            int sc = tid & 31;     // 8-row s-chunk
            int dgr = tid >> 5;    // 16-col d-group
#pragma unroll
            for (int j = 0; j < 16; ++j) {
                int col = dgr * 16 + j;
                int kv = kvb + (col >> 7), d = col & 127;
                bf16x8 o = *(const bf16x8*)(smem + col * 512 + ((sc ^ (col & 7)) << 4));
                *(bf16x8*)(Vo + ((size_t)(b * NKV + kv) * HD + d) * S_LEN + s0 + sc * 8) = o;
            }
        }
    }
}

// ---------------- causal GQA flash attention (longest-first, K+V double-buffered) --------
__global__ __launch_bounds__(256, 2) void attn_fwd(const bf16* __restrict__ Q,
                                                   const bf16* __restrict__ K,
                                                   const bf16* __restrict__ Vt,
                                                   bf16* __restrict__ O) {
    __shared__ __align__(16) bf16 Ks[2][64 * 128];   // 32 KB
    __shared__ __align__(16) bf16 Vs[2][128 * 64];   // 32 KB
    __shared__ __align__(16) bf16 Ps[4][32 * 64];    // 16 KB  -> 80 KB total, 2 blocks/CU

    int ord = blockIdx.x;             // 0..1023
    int qt = 15 - (ord >> 6);         // longest q-tiles dispatch first
    int bh = ord & 63;
    int h = bh & 31, b = bh >> 5;
    int kvh = h >> 2;
    int tid = threadIdx.x, lane = tid & 63, w = tid >> 6;
    int l15 = lane & 15, lg = lane >> 4, l7 = l15 & 7, lg4 = lg * 4;
    int q0 = qt * 128;
    int qbw = q0 + w * 32;

    const bf16* Qb = Q + ((size_t)(b * NH + h) * S_LEN) * HD;
    const bf16* Kb = K + ((size_t)(b * NKV + kvh) * S_LEN) * HD;
    const bf16* Vb = Vt + ((size_t)(b * NKV + kvh) * HD) * S_LEN;

    bf16x8 qf[2][4];
#pragma unroll
    for (int i = 0; i < 2; ++i)
#pragma unroll
        for (int ks = 0; ks < 4; ++ks)
            qf[i][ks] = *(const bf16x8*)(Qb + (size_t)(qbw + i * 16 + l15) * HD + ks * 32 + lg * 8);

    floatx4 accO[2][8] = {};
    float m_run[2] = {-1e30f, -1e30f}, l_run[2] = {0.f, 0.f};

    char* Pc = (char*)Ps[w];
    int nt = 2 * qt + 2;

    auto stageK = [&](int buf, int t) {
        int kv0 = t * 64;
#pragma unroll
        for (int it = 0; it < 4; ++it) {
            int o = it * 4096 + tid * 16;
            int r = o >> 8, pb = (o >> 4) & 15;
            int lb = pb ^ (r & 7);
            __builtin_amdgcn_global_load_lds((GV*)(Kb + (size_t)(kv0 + r) * HD + lb * 8),
                                             (SV*)((char*)Ks[buf] + o), 16, 0, 0);
        }
    };
    auto stageV = [&](int buf, int t) {
        int kv0 = t * 64;
#pragma unroll
        for (int it = 0; it < 4; ++it) {
            int o = it * 4096 + tid * 16;
            int d = o >> 7, pb = (o >> 4) & 7;
            int lb = pb ^ (d & 7);
            __builtin_amdgcn_global_load_lds((GV*)(Vb + (size_t)d * S_LEN + kv0 + lb * 8),
                                             (SV*)((char*)Vs[buf] + o), 16, 0, 0);
        }
    };

    stageK(0, 0);
    stageV(0, 0);

    for (int t = 0; t < nt; ++t) {
        int cur = t & 1;
        int kv0 = t * 64;
        bool more = (t + 1 < nt);
        if (more) { stageK(cur ^ 1, t + 1); stageV(cur ^ 1, t + 1); }
        if (more) asm volatile("s_waitcnt vmcnt(8)" ::: "memory");  // K(t),V(t) landed
        else      asm volatile("s_waitcnt vmcnt(0)" ::: "memory");
        SCHED_FENCE();
        BAR();

        const char* Kc = (const char*)Ks[cur];
        const char* Vc = (const char*)Vs[cur];
        floatx4 s[2][4] = {};
        __builtin_amdgcn_s_setprio(1);
#pragma unroll
        for (int nm = 0; nm < 4; ++nm)
#pragma unroll
            for (int ks = 0; ks < 4; ++ks) {
                bf16x8 kf = *(const bf16x8*)(Kc + (nm * 16 + l15) * 256 +
                                             ((((ks << 2) | lg) ^ l7) << 4));
                s[0][nm] = __builtin_amdgcn_mfma_f32_16x16x32_bf16(kf, qf[0][ks], s[0][nm], 0, 0, 0);
                s[1][nm] = __builtin_amdgcn_mfma_f32_16x16x32_bf16(kf, qf[1][ks], s[1][nm], 0, 0, 0);
            }
        __builtin_amdgcn_s_setprio(0);

#pragma unroll
        for (int i = 0; i < 2; ++i) {
            if (kv0 + 63 > qbw + i * 16) {
                int qg = qbw + i * 16 + l15;
#pragma unroll
                for (int nm = 0; nm < 4; ++nm)
#pragma unroll
                    for (int r = 0; r < 4; ++r)
                        if (kv0 + nm * 16 + lg4 + r > qg) s[i][nm][r] = -1e30f;
            }
            // tree max
            float t0 = fmaxf(fmaxf(s[i][0][0], s[i][0][1]), fmaxf(s[i][0][2], s[i][0][3]));
            float t1 = fmaxf(fmaxf(s[i][1][0], s[i][1][1]), fmaxf(s[i][1][2], s[i][1][3]));
            float t2 = fmaxf(fmaxf(s[i][2][0], s[i][2][1]), fmaxf(s[i][2][2], s[i][2][3]));
            float t3 = fmaxf(fmaxf(s[i][3][0], s[i][3][1]), fmaxf(s[i][3][2], s[i][3][3]));
            float pm = fmaxf(fmaxf(t0, t1), fmaxf(t2, t3));
            pm = fmaxf(pm, __shfl_xor(pm, 16));
            pm = fmaxf(pm, __shfl_xor(pm, 32));
            bool need = !__all(pm - m_run[i] <= 8.f);
            float corr = 1.f;
            if (need) {
                float mn = fmaxf(m_run[i], pm);
                corr = __expf(m_run[i] - mn);
                m_run[i] = mn;
            }
            float mn = m_run[i];
            float sum = 0.f;
#pragma unroll
            for (int nm = 0; nm < 4; ++nm) {
                bf16x4 pk;
#pragma unroll
                for (int r = 0; r < 4; ++r) {
                    float p = __expf(s[i][nm][r] - mn);
                    sum += p;
                    pk[r] = (bf16)p;
                }
                *(bf16x4*)(Pc + (i * 16 + l15) * 128 +
                           ((((nm << 1) | (lg >> 1)) ^ l7) << 4) + ((lg & 1) << 3)) = pk;
            }
            sum += __shfl_xor(sum, 16);
            sum += __shfl_xor(sum, 32);
            if (need) {
                l_run[i] = l_run[i] * corr + sum;
#pragma unroll
                for (int r = 0; r < 4; ++r) {
                    float cr = __shfl(corr, lg4 + r);
#pragma unroll
                    for (int g = 0; g < 8; ++g) accO[i][g][r] *= cr;
                }
            } else {
                l_run[i] += sum;
            }
        }

        asm volatile("s_waitcnt lgkmcnt(0)" ::: "memory");
        SCHED_FENCE();

        bf16x8 pf[2][2];
#pragma unroll
        for (int i = 0; i < 2; ++i)
#pragma unroll
            for (int ks = 0; ks < 2; ++ks)
                pf[i][ks] = *(const bf16x8*)(Pc + (i * 16 + l15) * 128 +
                                             ((((ks << 2) | lg) ^ l7) << 4));
        __builtin_amdgcn_s_setprio(1);
#pragma unroll
        for (int g = 0; g < 8; ++g)
#pragma unroll
            for (int ks = 0; ks < 2; ++ks) {
                bf16x8 vf = *(const bf16x8*)(Vc + (g * 16 + l15) * 128 +
                                             ((((ks << 2) | lg) ^ l7) << 4));
                accO[0][g] = __builtin_amdgcn_mfma_f32_16x16x32_bf16(pf[0][ks], vf, accO[0][g], 0, 0, 0);
                accO[1][g] = __builtin_amdgcn_mfma_f32_16x16x32_bf16(pf[1][ks], vf, accO[1][g], 0, 0, 0);
            }
        __builtin_amdgcn_s_setprio(0);
        BAR();
    }

#pragma unroll
    for (int i = 0; i < 2; ++i) {
        float inv = 1.f / l_run[i];
#pragma unroll
        for (int r = 0; r < 4; ++r) {
            float vinv = __shfl(inv, lg4 + r);
            int qg = qbw + i * 16 + lg4 + r;
            size_t ob = ((size_t)(b * S_LEN + qg) * NH + h) * HD;
#pragma unroll
            for (int g = 0; g < 8; ++g)
                O[ob + g * 16 + l15] = (bf16)(accO[i][g][r] * vinv);
        }
    }
}

extern "C" void kernel_launch(void* const* d_in, const int* in_sizes, int n_in,
                              void* d_out, int out_size, void* d_ws, size_t ws_size,
                              hipStream_t stream) {
    const float* hs   = (const float*)d_in[0];
    const float* cosp = (const float*)d_in[1];
    const float* sinp = (const float*)d_in[2];
    const float* wqkv = (const float*)d_in[3];
    const float* wo   = (const float*)d_in[4];
    float* out = (float*)d_out;

    char* ws = (char*)d_ws;
    size_t off = 0;
    auto alloc = [&](size_t bytes) {
        char* p = ws + off;
        off += (bytes + 255) & ~(size_t)255;
        return p;
    };
    const size_t n_hs = (size_t)B_DIM * S_LEN * HID;
    const size_t n_wqkv = (size_t)QKVW * HID;
    const size_t n_wo = (size_t)HID * QSZ;

    bf16* hs_b   = (bf16*)alloc(n_hs * 2);
    bf16* wqkv_b = (bf16*)alloc(n_wqkv * 2);
    bf16* wo_b   = (bf16*)alloc(n_wo * 2);
    bf16* Qb  = (bf16*)alloc((size_t)B_DIM * NH * S_LEN * HD * 2);
    bf16* Kb  = (bf16*)alloc((size_t)B_DIM * NKV * S_LEN * HD * 2);
    bf16* Vtb = (bf16*)alloc((size_t)B_DIM * NKV * HD * S_LEN * 2);
    bf16* attn_b = hs_b;  // hs_b dead after gemm1

    // convert only what gemm1 needs up front
    cvt2<<<1536, 256, 0, stream>>>(hs, hs_b, (int)(n_hs >> 2),
                                   wqkv, wqkv_b, (int)(n_wqkv >> 2));

    // GEMM1 + fused RoPE/layout epilogue. Extra 64 blocks convert w_o (f32->bf16),
    // backfilling the 1.5-round grid's idle CUs in round 2.
    const int ngemm1 = (4096 / 256) * (6144 / 256);  // 384
    gemm256<1, bf16><<<ngemm1 + 64, 512, 0, stream>>>(
        hs_b, wqkv_b, (bf16*)nullptr, Qb, Kb, Vtb, cosp, sinp,
        wo, wo_b, (int)(n_wo >> 2), ngemm1, B_DIM * S_LEN, QKVW, HID);

    attn_fwd<<<B_DIM * NH * (S_LEN / 128), 256, 0, stream>>>(Qb, Kb, Vtb, attn_b);

    gemm256<0, float><<<(4096 / 256) * (4096 / 256), 512, 0, stream>>>(
        attn_b, wo_b, out, nullptr, nullptr, nullptr, nullptr, nullptr,
        nullptr, nullptr, 0, (4096 / 256) * (4096 / 256),
        B_DIM * S_LEN, HID, HID);
}

// Round 18
// 457.913 us; speedup vs baseline: 1.1154x; 1.1154x over previous
//
#include <hip/hip_runtime.h>
#include <hip/hip_bf16.h>
#include <cstdint>

#define B_DIM 2
#define S_LEN 2048
#define HID 4096
#define NH 32
#define NKV 8
#define HD 128
#define QSZ (NH * HD)          // 4096
#define KVSZ (NKV * HD)        // 1024
#define QKVW (QSZ + 2 * KVSZ)  // 6144
#define SCALING 0.08838834764831845f

typedef __bf16 bf16;
typedef __bf16 bf16x4 __attribute__((ext_vector_type(4)));
typedef __bf16 bf16x8 __attribute__((ext_vector_type(8)));
typedef float floatx4 __attribute__((ext_vector_type(4)));

typedef __attribute__((address_space(1))) void GV;
typedef __attribute__((address_space(3))) void SV;

#define BAR() __builtin_amdgcn_s_barrier()
#define SCHED_FENCE() __builtin_amdgcn_sched_barrier(0)

// ---------------- fused f32 -> bf16 convert (2 buffers, 1 launch) ----------------
__global__ __launch_bounds__(256) void cvt2(const float* __restrict__ a, bf16* __restrict__ oa, int na4,
                                            const float* __restrict__ b, bf16* __restrict__ ob, int nb4) {
    int total = na4 + nb4;
    int stride = gridDim.x * blockDim.x;
    for (int i = blockIdx.x * blockDim.x + threadIdx.x; i < total; i += stride) {
        const float* src; bf16* dst; int j = i;
        if (j < na4) { src = a; dst = oa; }
        else { j -= na4; src = b; dst = ob; }
        float4 v = ((const float4*)src)[j];
        bf16x4 o;
        o[0] = (bf16)v.x; o[1] = (bf16)v.y; o[2] = (bf16)v.z; o[3] = (bf16)v.w;
        ((bf16x4*)dst)[j] = o;
    }
}

// ---------------- 256x256 GEMM, 4 barriers / 2 K-tiles (16x16x32 MFMA) ----------------
// Merged phase pairs: {P0;P1;BAR} {P2;P3;vmcnt;BAR} {P4;P5;BAR} {P6;P7;vmcnt;BAR}.
// WAR ledger: each stage's target region was last READ >=1 barrier earlier, and those
// reads drain in-phase via their consuming MFMA's lgkm wait before the barrier.
// MODE 0: plain C write. MODE 1: fused RoPE/QKV epilogue. blockIdx >= ngemm: backfill cvt.
template <int MODE, typename OutT>
__global__ __launch_bounds__(512, 2) void gemm256(const bf16* __restrict__ A,
                                                  const bf16* __restrict__ Bm,
                                                  OutT* __restrict__ C,
                                                  bf16* __restrict__ Qo,
                                                  bf16* __restrict__ Ko,
                                                  bf16* __restrict__ Vo,
                                                  const float* __restrict__ cosp,
                                                  const float* __restrict__ sinp,
                                                  const float* __restrict__ cvt_src,
                                                  bf16* __restrict__ cvt_dst,
                                                  int cvt_n4, int ngemm,
                                                  int M, int N, int K) {
    __shared__ __align__(16) char smem[131072];
    (void)M;
    int bid = blockIdx.x;
    int tid = threadIdx.x;
    if (bid >= ngemm) {
        // ---- backfill converter block: runs on CUs idle during gemm round 2 ----
        int stride = (gridDim.x - ngemm) * 512;
        for (int i = (bid - ngemm) * 512 + tid; i < cvt_n4; i += stride) {
            float4 v = ((const float4*)cvt_src)[i];
            bf16x4 o;
            o[0] = (bf16)v.x; o[1] = (bf16)v.y; o[2] = (bf16)v.z; o[3] = (bf16)v.w;
            ((bf16x4*)cvt_dst)[i] = o;
        }
        return;
    }
    int tiles_n = N >> 8;
    int wg = (bid & 7) * (ngemm >> 3) + (bid >> 3);  // XCD chunking (ngemm % 8 == 0)
    int bm = wg / tiles_n, bn = wg % tiles_n;
    int lane = tid & 63, w = tid >> 6;
    int l15 = lane & 15, lg = lane >> 4, l7 = l15 & 7;
    int wm = w >> 2, wn = w & 3;
    const bf16* Ab = A + (size_t)bm * 256 * K;
    const bf16* Bb = Bm + (size_t)bn * 256 * K;

    auto AsP = [&](int buf, int h) -> char* { return smem + (buf * 2 + h) * 16384; };
    auto BsP = [&](int buf, int h) -> char* { return smem + 65536 + (buf * 2 + h) * 16384; };

    int o_lo = tid * 16, o_hi = o_lo + 8192;
    int r_lo = o_lo >> 7, r_hi = o_hi >> 7;
    int eo0 = r_lo * K + ((((o_lo >> 4) & 7) ^ (r_lo & 7)) << 3);
    int eo1 = r_hi * K + ((((o_hi >> 4) & 7) ^ (r_hi & 7)) << 3);
    const bf16* AbH[2] = {Ab, Ab + (size_t)128 * K};
    const bf16* BbH[2] = {Bb, Bb + (size_t)128 * K};

    auto stageA = [&](int buf, int h, int kt) {
        const bf16* base = AbH[h] + kt * 64;
        __builtin_amdgcn_global_load_lds((GV*)(base + eo0), (SV*)(AsP(buf, h) + o_lo), 16, 0, 0);
        __builtin_amdgcn_global_load_lds((GV*)(base + eo1), (SV*)(AsP(buf, h) + o_hi), 16, 0, 0);
    };
    auto stageB = [&](int buf, int h, int kt) {
        const bf16* base = BbH[h] + kt * 64;
        __builtin_amdgcn_global_load_lds((GV*)(base + eo0), (SV*)(BsP(buf, h) + o_lo), 16, 0, 0);
        __builtin_amdgcn_global_load_lds((GV*)(base + eo1), (SV*)(BsP(buf, h) + o_hi), 16, 0, 0);
    };
    auto rdA = [&](int buf, int fr, int kk) -> bf16x8 {
        int off = (fr * 16 + l15) * 128 + ((((kk << 2) | lg) ^ l7) << 4);
        return *(const bf16x8*)(AsP(buf, wm) + off);
    };
    auto rdB = [&](int buf, int fc, int kk) -> bf16x8 {
        int off = ((wn & 1) * 64 + fc * 16 + l15) * 128 + ((((kk << 2) | lg) ^ l7) << 4);
        return *(const bf16x8*)(BsP(buf, wn >> 1) + off);
    };

    floatx4 acc[8][4] = {};
    bf16x8 aF[4][2], bF[4][2];
    int nk = K >> 6, niter = nk >> 1;

    stageA(0, 0, 0); stageA(0, 1, 0); stageB(0, 0, 0); stageB(0, 1, 0);
    stageB(1, 0, 1); stageB(1, 1, 1);
    asm volatile("s_waitcnt vmcnt(4)" ::: "memory");
    SCHED_FENCE();
    BAR();

    auto quad = [&](int ra, int ca) {
        __builtin_amdgcn_s_setprio(1);
#pragma unroll
        for (int fr = 0; fr < 4; ++fr)
#pragma unroll
            for (int fc = 0; fc < 2; ++fc)
#pragma unroll
                for (int kk = 0; kk < 2; ++kk)
                    acc[ra * 4 + fr][ca * 2 + fc] = __builtin_amdgcn_mfma_f32_16x16x32_bf16(
                        aF[fr][kk], bF[ca * 2 + fc][kk], acc[ra * 4 + fr][ca * 2 + fc], 0, 0, 0);
        __builtin_amdgcn_s_setprio(0);
    };

    for (int i = 0; i < niter; ++i) {
        bool nl = (i + 1 < niter);
        int kt1 = 2 * i + 1, kt2 = 2 * i + 2, kt3 = 2 * i + 3;
        // P0 (no barrier after)
#pragma unroll
        for (int fr = 0; fr < 4; ++fr)
#pragma unroll
            for (int kk = 0; kk < 2; ++kk) aF[fr][kk] = rdA(0, fr, kk);
#pragma unroll
        for (int fc = 0; fc < 2; ++fc)
#pragma unroll
            for (int kk = 0; kk < 2; ++kk) bF[fc][kk] = rdB(0, fc, kk);
        stageA(1, 0, kt1);
        quad(0, 0);
        // P1
#pragma unroll
        for (int fc = 2; fc < 4; ++fc)
#pragma unroll
            for (int kk = 0; kk < 2; ++kk) bF[fc][kk] = rdB(0, fc, kk);
        stageA(1, 1, kt1);
        quad(0, 1); BAR();
        // P2 (no barrier after)
#pragma unroll
        for (int fr = 0; fr < 4; ++fr)
#pragma unroll
            for (int kk = 0; kk < 2; ++kk) aF[fr][kk] = rdA(0, 4 + fr, kk);
        if (nl) stageB(0, 0, kt2);
        quad(1, 0);
        // P3
        if (nl) stageB(0, 1, kt2);
        quad(1, 1);
        if (nl) asm volatile("s_waitcnt vmcnt(4)" ::: "memory");
        else    asm volatile("s_waitcnt vmcnt(0)" ::: "memory");
        SCHED_FENCE();
        BAR();
        // P4 (no barrier after)
#pragma unroll
        for (int fr = 0; fr < 4; ++fr)
#pragma unroll
            for (int kk = 0; kk < 2; ++kk) aF[fr][kk] = rdA(1, fr, kk);
#pragma unroll
        for (int fc = 0; fc < 2; ++fc)
#pragma unroll
            for (int kk = 0; kk < 2; ++kk) bF[fc][kk] = rdB(1, fc, kk);
        if (nl) stageA(0, 0, kt2);
        quad(0, 0);
        // P5
#pragma unroll
        for (int fc = 2; fc < 4; ++fc)
#pragma unroll
            for (int kk = 0; kk < 2; ++kk) bF[fc][kk] = rdB(1, fc, kk);
        if (nl) stageA(0, 1, kt2);
        quad(0, 1); BAR();
        // P6 (no barrier after)
#pragma unroll
        for (int fr = 0; fr < 4; ++fr)
#pragma unroll
            for (int kk = 0; kk < 2; ++kk) aF[fr][kk] = rdA(1, 4 + fr, kk);
        if (nl) stageB(1, 0, kt3);
        quad(1, 0);
        // P7
        if (nl) stageB(1, 1, kt3);
        quad(1, 1);
        asm volatile("s_waitcnt vmcnt(4)" ::: "memory");
        SCHED_FENCE();
        BAR();
    }

    if constexpr (MODE == 0) {
        int brow = bm * 256 + wm * 128, bcol = bn * 256 + wn * 64;
#pragma unroll
        for (int fr = 0; fr < 8; ++fr)
#pragma unroll
            for (int fc = 0; fc < 4; ++fc) {
                int col = bcol + fc * 16 + l15;
#pragma unroll
                for (int r = 0; r < 4; ++r) {
                    int row = brow + fr * 16 + lg * 4 + r;
                    C[(size_t)row * N + col] = (OutT)acc[fr][fc][r];
                }
            }
    } else {
        __syncthreads();  // all LDS reads of As/Bs done; safe to overwrite
        int b = (bm * 256) >> 11, s0 = (bm * 256) & (S_LEN - 1);
        int colb = wn * 64, rowb = wm * 128;
        if (bn < 20) {
            // ---- row-major bounce: Cb[row][swz(col)] ----
            bf16* Cb = (bf16*)smem;
#pragma unroll
            for (int fr = 0; fr < 8; ++fr)
#pragma unroll
                for (int fc = 0; fc < 4; ++fc) {
                    int col = colb + fc * 16 + l15;
                    int br = rowb + fr * 16 + lg * 4;
#pragma unroll
                    for (int r = 0; r < 4; ++r) {
                        int row = br + r;
                        Cb[row * 256 + ((((col >> 3) ^ (row & 7)) << 3) | (col & 7))] =
                            (bf16)acc[fr][fc][r];
                    }
                }
            __syncthreads();
            // ---- Q (bn<16) or K (16..19): RoPE + write [.,H,S,D] ----
            bool isQ = (bn < 16);
            int hh = w & 1;
            int c = l15, d0 = c * 8;
            float scale = isQ ? SCALING : 1.0f;
            float sgn = (c < 8) ? -1.0f : 1.0f;
            bf16* Ob = isQ ? (Qo + ((size_t)(b * NH + bn * 2 + hh) * S_LEN) * HD)
                           : (Ko + ((size_t)(b * NKV + (bn - 16) * 2 + hh) * S_LEN) * HD);
            int slot_s = hh * 16 + c, slot_p = hh * 16 + (c ^ 8);
#pragma unroll
            for (int rd = 0; rd < 16; ++rd) {
                int row = (w >> 1) * 64 + rd * 4 + lg;
                int s = s0 + row;
                bf16x8 xs = *(const bf16x8*)(Cb + row * 256 + ((slot_s ^ (row & 7)) << 3));
                bf16x8 xp = *(const bf16x8*)(Cb + row * 256 + ((slot_p ^ (row & 7)) << 3));
                const float* cr = cosp + ((size_t)b * S_LEN + s) * HD + d0;
                const float* sr = sinp + ((size_t)b * S_LEN + s) * HD + d0;
                float4 c0 = *(const float4*)cr, c1 = *(const float4*)(cr + 4);
                float4 s0v = *(const float4*)sr, s1v = *(const float4*)(sr + 4);
                float cv[8] = {c0.x, c0.y, c0.z, c0.w, c1.x, c1.y, c1.z, c1.w};
                float sv[8] = {s0v.x, s0v.y, s0v.z, s0v.w, s1v.x, s1v.y, s1v.z, s1v.w};
                bf16x8 o;
#pragma unroll
                for (int e = 0; e < 8; ++e)
                    o[e] = (bf16)(((float)xs[e] * cv[e] + sgn * (float)xp[e] * sv[e]) * scale);
                *(bf16x8*)(Ob + (size_t)s * HD + d0) = o;
            }
        } else {
            // ---- V (bn 20..23): transposed bounce Cbt[col][swz(row)] -> Vt[B,NKV,HD,S] ----
#pragma unroll
            for (int fr = 0; fr < 8; ++fr)
#pragma unroll
                for (int fc = 0; fc < 4; ++fc) {
                    int col = colb + fc * 16 + l15;
                    int br = rowb + fr * 16 + lg * 4;
#pragma unroll
                    for (int r = 0; r < 4; ++r) {
                        int row = br + r;
                        *(bf16*)(smem + col * 512 +
                                 (((((row >> 3) ^ (col & 7)) << 4) | ((row & 7) << 1)))) =
                            (bf16)acc[fr][fc][r];
                    }
                }
            __syncthreads();
            int kvb = (bn - 20) * 2;
            int sc = tid & 31;     // 8-row s-chunk
            int dgr = tid >> 5;    // 16-col d-group
#pragma unroll
            for (int j = 0; j < 16; ++j) {
                int col = dgr * 16 + j;
                int kv = kvb + (col >> 7), d = col & 127;
                bf16x8 o = *(const bf16x8*)(smem + col * 512 + ((sc ^ (col & 7)) << 4));
                *(bf16x8*)(Vo + ((size_t)(b * NKV + kv) * HD + d) * S_LEN + s0 + sc * 8) = o;
            }
        }
    }
}

// ---------------- causal GQA flash attention (longest-first, K+V double-buffered) --------
__global__ __launch_bounds__(256, 2) void attn_fwd(const bf16* __restrict__ Q,
                                                   const bf16* __restrict__ K,
                                                   const bf16* __restrict__ Vt,
                                                   bf16* __restrict__ O) {
    __shared__ __align__(16) bf16 Ks[2][64 * 128];   // 32 KB
    __shared__ __align__(16) bf16 Vs[2][128 * 64];   // 32 KB
    __shared__ __align__(16) bf16 Ps[4][32 * 64];    // 16 KB  -> 80 KB total, 2 blocks/CU

    int ord = blockIdx.x;             // 0..1023
    int qt = 15 - (ord >> 6);         // longest q-tiles dispatch first
    int bh = ord & 63;
    int h = bh & 31, b = bh >> 5;
    int kvh = h >> 2;
    int tid = threadIdx.x, lane = tid & 63, w = tid >> 6;
    int l15 = lane & 15, lg = lane >> 4, l7 = l15 & 7, lg4 = lg * 4;
    int q0 = qt * 128;
    int qbw = q0 + w * 32;

    const bf16* Qb = Q + ((size_t)(b * NH + h) * S_LEN) * HD;
    const bf16* Kb = K + ((size_t)(b * NKV + kvh) * S_LEN) * HD;
    const bf16* Vb = Vt + ((size_t)(b * NKV + kvh) * HD) * S_LEN;

    bf16x8 qf[2][4];
#pragma unroll
    for (int i = 0; i < 2; ++i)
#pragma unroll
        for (int ks = 0; ks < 4; ++ks)
            qf[i][ks] = *(const bf16x8*)(Qb + (size_t)(qbw + i * 16 + l15) * HD + ks * 32 + lg * 8);

    floatx4 accO[2][8] = {};
    float m_run[2] = {-1e30f, -1e30f}, l_run[2] = {0.f, 0.f};

    char* Pc = (char*)Ps[w];
    int nt = 2 * qt + 2;

    auto stageK = [&](int buf, int t) {
        int kv0 = t * 64;
#pragma unroll
        for (int it = 0; it < 4; ++it) {
            int o = it * 4096 + tid * 16;
            int r = o >> 8, pb = (o >> 4) & 15;
            int lb = pb ^ (r & 7);
            __builtin_amdgcn_global_load_lds((GV*)(Kb + (size_t)(kv0 + r) * HD + lb * 8),
                                             (SV*)((char*)Ks[buf] + o), 16, 0, 0);
        }
    };
    auto stageV = [&](int buf, int t) {
        int kv0 = t * 64;
#pragma unroll
        for (int it = 0; it < 4; ++it) {
            int o = it * 4096 + tid * 16;
            int d = o >> 7, pb = (o >> 4) & 7;
            int lb = pb ^ (d & 7);
            __builtin_amdgcn_global_load_lds((GV*)(Vb + (size_t)d * S_LEN + kv0 + lb * 8),
                                             (SV*)((char*)Vs[buf] + o), 16, 0, 0);
        }
    };

    stageK(0, 0);
    stageV(0, 0);

    for (int t = 0; t < nt; ++t) {
        int cur = t & 1;
        int kv0 = t * 64;
        bool more = (t + 1 < nt);
        if (more) { stageK(cur ^ 1, t + 1); stageV(cur ^ 1, t + 1); }
        if (more) asm volatile("s_waitcnt vmcnt(8)" ::: "memory");  // K(t),V(t) landed
        else      asm volatile("s_waitcnt vmcnt(0)" ::: "memory");
        SCHED_FENCE();
        BAR();

        const char* Kc = (const char*)Ks[cur];
        const char* Vc = (const char*)Vs[cur];
        floatx4 s[2][4] = {};
        __builtin_amdgcn_s_setprio(1);
#pragma unroll
        for (int nm = 0; nm < 4; ++nm)
#pragma unroll
            for (int ks = 0; ks < 4; ++ks) {
                bf16x8 kf = *(const bf16x8*)(Kc + (nm * 16 + l15) * 256 +
                                             ((((ks << 2) | lg) ^ l7) << 4));
                s[0][nm] = __builtin_amdgcn_mfma_f32_16x16x32_bf16(kf, qf[0][ks], s[0][nm], 0, 0, 0);
                s[1][nm] = __builtin_amdgcn_mfma_f32_16x16x32_bf16(kf, qf[1][ks], s[1][nm], 0, 0, 0);
            }
        __builtin_amdgcn_s_setprio(0);

#pragma unroll
        for (int i = 0; i < 2; ++i) {
            if (kv0 + 63 > qbw + i * 16) {
                int qg = qbw + i * 16 + l15;
#pragma unroll
                for (int nm = 0; nm < 4; ++nm)
#pragma unroll
                    for (int r = 0; r < 4; ++r)
                        if (kv0 + nm * 16 + lg4 + r > qg) s[i][nm][r] = -1e30f;
            }
            // tree max
            float t0 = fmaxf(fmaxf(s[i][0][0], s[i][0][1]), fmaxf(s[i][0][2], s[i][0][3]));
            float t1 = fmaxf(fmaxf(s[i][1][0], s[i][1][1]), fmaxf(s[i][1][2], s[i][1][3]));
            float t2 = fmaxf(fmaxf(s[i][2][0], s[i][2][1]), fmaxf(s[i][2][2], s[i][2][3]));
            float t3 = fmaxf(fmaxf(s[i][3][0], s[i][3][1]), fmaxf(s[i][3][2], s[i][3][3]));
            float pm = fmaxf(fmaxf(t0, t1), fmaxf(t2, t3));
            pm = fmaxf(pm, __shfl_xor(pm, 16));
            pm = fmaxf(pm, __shfl_xor(pm, 32));
            bool need = !__all(pm - m_run[i] <= 8.f);
            float corr = 1.f;
            if (need) {
                float mn = fmaxf(m_run[i], pm);
                corr = __expf(m_run[i] - mn);
                m_run[i] = mn;
            }
            float mn = m_run[i];
            float sum = 0.f;
#pragma unroll
            for (int nm = 0; nm < 4; ++nm) {
                bf16x4 pk;
#pragma unroll
                for (int r = 0; r < 4; ++r) {
                    float p = __expf(s[i][nm][r] - mn);
                    sum += p;
                    pk[r] = (bf16)p;
                }
                *(bf16x4*)(Pc + (i * 16 + l15) * 128 +
                           ((((nm << 1) | (lg >> 1)) ^ l7) << 4) + ((lg & 1) << 3)) = pk;
            }
            sum += __shfl_xor(sum, 16);
            sum += __shfl_xor(sum, 32);
            if (need) {
                l_run[i] = l_run[i] * corr + sum;
#pragma unroll
                for (int r = 0; r < 4; ++r) {
                    float cr = __shfl(corr, lg4 + r);
#pragma unroll
                    for (int g = 0; g < 8; ++g) accO[i][g][r] *= cr;
                }
            } else {
                l_run[i] += sum;
            }
        }

        asm volatile("s_waitcnt lgkmcnt(0)" ::: "memory");
        SCHED_FENCE();

        bf16x8 pf[2][2];
#pragma unroll
        for (int i = 0; i < 2; ++i)
#pragma unroll
            for (int ks = 0; ks < 2; ++ks)
                pf[i][ks] = *(const bf16x8*)(Pc + (i * 16 + l15) * 128 +
                                             ((((ks << 2) | lg) ^ l7) << 4));
        __builtin_amdgcn_s_setprio(1);
#pragma unroll
        for (int g = 0; g < 8; ++g)
#pragma unroll
            for (int ks = 0; ks < 2; ++ks) {
                bf16x8 vf = *(const bf16x8*)(Vc + (g * 16 + l15) * 128 +
                                             ((((ks << 2) | lg) ^ l7) << 4));
                accO[0][g] = __builtin_amdgcn_mfma_f32_16x16x32_bf16(pf[0][ks], vf, accO[0][g], 0, 0, 0);
                accO[1][g] = __builtin_amdgcn_mfma_f32_16x16x32_bf16(pf[1][ks], vf, accO[1][g], 0, 0, 0);
            }
        __builtin_amdgcn_s_setprio(0);
        BAR();
    }

#pragma unroll
    for (int i = 0; i < 2; ++i) {
        float inv = 1.f / l_run[i];
#pragma unroll
        for (int r = 0; r < 4; ++r) {
            float vinv = __shfl(inv, lg4 + r);
            int qg = qbw + i * 16 + lg4 + r;
            size_t ob = ((size_t)(b * S_LEN + qg) * NH + h) * HD;
#pragma unroll
            for (int g = 0; g < 8; ++g)
                O[ob + g * 16 + l15] = (bf16)(accO[i][g][r] * vinv);
        }
    }
}

extern "C" void kernel_launch(void* const* d_in, const int* in_sizes, int n_in,
                              void* d_out, int out_size, void* d_ws, size_t ws_size,
                              hipStream_t stream) {
    const float* hs   = (const float*)d_in[0];
    const float* cosp = (const float*)d_in[1];
    const float* sinp = (const float*)d_in[2];
    const float* wqkv = (const float*)d_in[3];
    const float* wo   = (const float*)d_in[4];
    float* out = (float*)d_out;

    char* ws = (char*)d_ws;
    size_t off = 0;
    auto alloc = [&](size_t bytes) {
        char* p = ws + off;
        off += (bytes + 255) & ~(size_t)255;
        return p;
    };
    const size_t n_hs = (size_t)B_DIM * S_LEN * HID;
    const size_t n_wqkv = (size_t)QKVW * HID;
    const size_t n_wo = (size_t)HID * QSZ;

    bf16* hs_b   = (bf16*)alloc(n_hs * 2);
    bf16* wqkv_b = (bf16*)alloc(n_wqkv * 2);
    bf16* wo_b   = (bf16*)alloc(n_wo * 2);
    bf16* Qb  = (bf16*)alloc((size_t)B_DIM * NH * S_LEN * HD * 2);
    bf16* Kb  = (bf16*)alloc((size_t)B_DIM * NKV * S_LEN * HD * 2);
    bf16* Vtb = (bf16*)alloc((size_t)B_DIM * NKV * HD * S_LEN * 2);
    bf16* attn_b = hs_b;  // hs_b dead after gemm1

    // convert only what gemm1 needs up front
    cvt2<<<1536, 256, 0, stream>>>(hs, hs_b, (int)(n_hs >> 2),
                                   wqkv, wqkv_b, (int)(n_wqkv >> 2));

    // GEMM1 + fused RoPE/layout epilogue. Extra 64 blocks convert w_o (f32->bf16),
    // backfilling the 1.5-round grid's idle CUs in round 2.
    const int ngemm1 = (4096 / 256) * (6144 / 256);  // 384
    gemm256<1, bf16><<<ngemm1 + 64, 512, 0, stream>>>(
        hs_b, wqkv_b, (bf16*)nullptr, Qb, Kb, Vtb, cosp, sinp,
        wo, wo_b, (int)(n_wo >> 2), ngemm1, B_DIM * S_LEN, QKVW, HID);

    attn_fwd<<<B_DIM * NH * (S_LEN / 128), 256, 0, stream>>>(Qb, Kb, Vtb, attn_b);

    gemm256<0, float><<<(4096 / 256) * (4096 / 256), 512, 0, stream>>>(
        attn_b, wo_b, out, nullptr, nullptr, nullptr, nullptr, nullptr,
        nullptr, nullptr, 0, (4096 / 256) * (4096 / 256),
        B_DIM * S_LEN, HID, HID);
}